// Round 10
// baseline (129.154 us; speedup 1.0000x reference)
//
#include <hip/hip_runtime.h>
#include <hip/hip_bf16.h>
#include <stdint.h>

#define K_DIM 1024
#define N_DIM 1024

typedef __attribute__((ext_vector_type(8))) short  short8;
typedef __attribute__((ext_vector_type(4))) float  f32x4;
typedef __attribute__((ext_vector_type(4))) unsigned int u32x4;

__device__ __forceinline__ ushort f2bf(float f) {
  union { float f; uint32_t u; } v; v.f = f;
  uint32_t r = v.u + 0x7FFFu + ((v.u >> 16) & 1u);
  return (ushort)(r >> 16);
}
__device__ __forceinline__ uint32_t pack_bf2(float a, float b) {
  __hip_bfloat162 h = __float22bfloat162_rn(make_float2(a, b));
  union { __hip_bfloat162 h; uint32_t u; } c; c.h = h;
  return c.u;
}

// ---------------- kernel 1: materialize Toeplitz matrix as bf16 -------------
__global__ __launch_bounds__(256) void build_T_kernel(
    const float* __restrict__ fr, const float* __restrict__ fc,
    ushort* __restrict__ T) {
  int idx = blockIdx.x * 256 + threadIdx.x;
  int o  = idx >> 7;
  int i0 = (idx & 127) << 3;
  short8 v;
#pragma unroll
  for (int j = 0; j < 8; ++j) {
    int d = o - (i0 + j);
    float f = (d >= 0) ? fc[d] : fr[-d];
    v[j] = (short)f2bf(f);
  }
  *reinterpret_cast<short8*>(T + (size_t)idx * 8) = v;
}

// ---------------- kernel 1b: convert x fp32 -> bf16 -------------------------
__global__ __launch_bounds__(256) void convert_x_kernel(
    const float* __restrict__ X, ushort* __restrict__ XB) {
  size_t idx = ((size_t)blockIdx.x * 256 + threadIdx.x) * 8;
  const size_t stride = (size_t)2048 * 256 * 8;
#pragma unroll
  for (int it = 0; it < 8; ++it) {
    f32x4 a = *reinterpret_cast<const f32x4*>(X + idx);
    f32x4 b = *reinterpret_cast<const f32x4*>(X + idx + 4);
    u32x4 p;
    p.x = pack_bf2(a.x, a.y); p.y = pack_bf2(a.z, a.w);
    p.z = pack_bf2(b.x, b.y); p.w = pack_bf2(b.z, b.w);
    *reinterpret_cast<u32x4*>(XB + idx) = p;
    idx += stride;
  }
}

// ---- kernel 2: 256x256 bf16; pipelined reads; A 3-buf, B 2-buf (160 KiB) ---
__global__ __launch_bounds__(512, 2) void gemm_bf16_p8(
    const ushort* __restrict__ XB, const ushort* __restrict__ T,
    const float* __restrict__ bias, float* __restrict__ Out) {
  // A bufs: 3 x 32 KiB @ 0; B bufs: 2 x 32 KiB @ 98304. Total 160 KiB.
  __shared__ alignas(16) char smem[163840];

  const int tid  = threadIdx.x;
  const int lane = tid & 63;
  const int wv   = tid >> 6;
  const int wm   = wv >> 2, wn = wv & 3;      // 2x4 wave grid, 128x64 tiles
  const int cc   = lane & 15, kg = lane >> 4;

  // XCD swizzle: 512 blocks = 8 xcd * 64; 4 consecutive share an m-panel.
  const int swz = (blockIdx.x & 7) * 64 + (blockIdx.x >> 3);
  const int m0 = (swz >> 2) * 256;
  const int n0 = (swz & 3) * 256;

  const int r0 = tid >> 3;
  const int kbs = (((tid & 7) * 16) ^ ((r0 & 7) << 4)) >> 1;  // pre-swizzled k
  const ushort* aSrc = XB + (size_t)(m0 + r0) * K_DIM + kbs;
  const ushort* bSrc = T  + (size_t)(n0 + r0) * K_DIM + kbs;
  const int dOff = tid * 16;

  const int kx0 = (kg * 16) ^ ((cc & 7) << 4);
  const int kx1 = (64 + kg * 16) ^ ((cc & 7) << 4);
  const int aRow = (wm * 128 + cc) * 128;          // + mf*2048
  const int bRow = (wn * 64 + cc) * 128;           // + nf*2048

  short8 a03[4][2], a47[4][2], b01[2][2], b23[2][2];
  f32x4  acc[8][4] = {};

  int aC = 0, aN = 32768, aS = 65536;              // A buffer byte bases
  int bC = 98304, bN = 131072;                     // B buffer byte bases

#define SB0() __builtin_amdgcn_sched_barrier(0)
#define BAR() __builtin_amdgcn_s_barrier()
#define GATE8 asm volatile("s_waitcnt vmcnt(8)" ::: "memory")
#define GATE6 asm volatile("s_waitcnt vmcnt(6)" ::: "memory")
#define GATE4 asm volatile("s_waitcnt vmcnt(4)" ::: "memory")
#define GATE0 asm volatile("s_waitcnt vmcnt(0)" ::: "memory")

#define RD(base, off) (*reinterpret_cast<const short8*>(smem + (base) + (off)))

#define READ_A(BASE, arr, mfb)                                              \
  { _Pragma("unroll")                                                       \
    for (int mf = 0; mf < 4; ++mf) {                                        \
      arr[mf][0] = RD(BASE, aRow + ((mfb) + mf) * 2048 + kx0);              \
      arr[mf][1] = RD(BASE, aRow + ((mfb) + mf) * 2048 + kx1);              \
    } }

#define READ_B(BASE, arr, nfb)                                              \
  { _Pragma("unroll")                                                       \
    for (int nf = 0; nf < 2; ++nf) {                                        \
      arr[nf][0] = RD(BASE, bRow + ((nfb) + nf) * 2048 + kx0);              \
      arr[nf][1] = RD(BASE, bRow + ((nfb) + nf) * 2048 + kx1);              \
    } }

#define STAGE(SRC, kt, h, BASE)                                             \
  { _Pragma("unroll")                                                       \
    for (int s = 0; s < 2; ++s) {                                           \
      const ushort* src = (SRC) + (size_t)((h) * 128 + s * 64) * K_DIM + (kt) * 64; \
      char* dst = smem + (BASE) + (h) * 16384 + s * 8192 + dOff;            \
      __builtin_amdgcn_global_load_lds(                                     \
          (const __attribute__((address_space(1))) void*)src,               \
          (__attribute__((address_space(3))) void*)dst, 16, 0, 0);          \
    } }

#define MFMA16(Aa, Bb, mfb, nfb)                                            \
  { __builtin_amdgcn_s_setprio(1);                                         \
    _Pragma("unroll")                                                       \
    for (int mf = 0; mf < 4; ++mf)                                          \
      _Pragma("unroll")                                                     \
      for (int nf = 0; nf < 2; ++nf) {                                      \
        acc[(mfb) + mf][(nfb) + nf] = __builtin_amdgcn_mfma_f32_16x16x32_bf16( \
            Aa[mf][0], Bb[nf][0], acc[(mfb) + mf][(nfb) + nf], 0, 0, 0);    \
        acc[(mfb) + mf][(nfb) + nf] = __builtin_amdgcn_mfma_f32_16x16x32_bf16( \
            Aa[mf][1], Bb[nf][1], acc[(mfb) + mf][(nfb) + nf], 0, 0, 0);    \
      }                                                                     \
    __builtin_amdgcn_s_setprio(0); }

// GROUP: 4 phases for tile t. Reads are issued one phase before consumption;
// no manual lgkm (compiler emits dependency-counted waits). Stages: 1
// half-tile per phase into A-stage buf (t+2) / current B buf (free after ph1).
// Gate ledger (loads, steady state): G2 vmcnt(8) retires A(t+1) before ph3's
// read; G3 vmcnt(6) retires B(t+1) before ph4's trailing b01 read.
#define GROUP(t, DOSTG, G2STMT, G3STMT, DONEXT)                             \
  { /* ph1: MFMA(a03,b01); read b23(t); stage A(t+2).h0 */                  \
    READ_B(bC, b23, 2);                                                     \
    if (DOSTG) STAGE(aSrc, (t) + 2, 0, aS);                                 \
    SB0(); BAR(); SB0();                                                    \
    MFMA16(a03, b01, 0, 0);                                                 \
    SB0(); BAR(); SB0();                                                    \
    /* ph2: MFMA(a03,b23); read a47(t); stage A(t+2).h1 */                  \
    READ_A(aC, a47, 4);                                                     \
    if (DOSTG) STAGE(aSrc, (t) + 2, 1, aS);                                 \
    SB0(); BAR(); SB0();                                                    \
    MFMA16(a03, b23, 0, 2);                                                 \
    G2STMT; SB0(); BAR(); SB0();                                            \
    /* ph3: MFMA(a47,b23); read a03(t+1); stage B(t+2).h0 */                \
    if (DONEXT) READ_A(aN, a03, 0);                                         \
    if (DOSTG) STAGE(bSrc, (t) + 2, 0, bC);                                 \
    SB0(); BAR(); SB0();                                                    \
    MFMA16(a47, b23, 4, 2);                                                 \
    G3STMT; SB0(); BAR(); SB0();                                            \
    /* ph4: MFMA(a47,b01); trailing read b01(t+1); stage B(t+2).h1 */       \
    if (DOSTG) STAGE(bSrc, (t) + 2, 1, bC);                                 \
    SB0(); BAR(); SB0();                                                    \
    MFMA16(a47, b01, 4, 0);                                                 \
    if (DONEXT) READ_B(bN, b01, 0);                                         \
    SB0(); BAR(); SB0();                                                    \
  }

  // ---- prologue: stage tiles 0,1 (A+B); drain tile 0; preload a03/b01 ----
  STAGE(aSrc, 0, 0, 0);      SB0();
  STAGE(aSrc, 0, 1, 0);      SB0();
  STAGE(bSrc, 0, 0, 98304);  SB0();
  STAGE(bSrc, 0, 1, 98304);  SB0();
  STAGE(aSrc, 1, 0, 32768);  SB0();
  STAGE(aSrc, 1, 1, 32768);  SB0();
  STAGE(bSrc, 1, 0, 131072); SB0();
  STAGE(bSrc, 1, 1, 131072); SB0();
  GATE8;                      // drain A(0)+B(0); keep A(1)+B(1) in flight
  SB0(); BAR(); SB0();
  READ_A(aC, a03, 0);
  READ_B(bC, b01, 0);

#pragma unroll 1
  for (int t = 0; t < 14; ++t) {
    GROUP(t, 1, GATE8, GATE6, 1);
    int tmp = aC; aC = aN; aN = aS; aS = tmp;
    tmp = bC; bC = bN; bN = tmp;
  }
  // tile 14: no stages; gates retire A(15) then B(15)
  GROUP(14, 0, GATE4, GATE0, 1);
  { int tmp = aC; aC = aN; aN = aS; aS = tmp; tmp = bC; bC = bN; bN = tmp; }
  // tile 15: no stages, no gates, no next reads
  GROUP(15, 0, (void)0, (void)0, 0);

  // ---- epilogue: bias + fp32 store ----
#pragma unroll
  for (int nf = 0; nf < 4; ++nf) {
    const int col = n0 + wn * 64 + nf * 16 + cc;
    const float bv = bias[col];
#pragma unroll
    for (int mf = 0; mf < 8; ++mf) {
      const int row0 = m0 + wm * 128 + mf * 16 + kg * 4;
      float* op = Out + (size_t)row0 * N_DIM + col;
#pragma unroll
      for (int j = 0; j < 4; ++j)
        op[(size_t)j * N_DIM] = acc[mf][nf][j] + bv;
    }
  }
#undef GROUP
#undef MFMA16
#undef STAGE
#undef READ_A
#undef READ_B
#undef RD
#undef SB0
#undef BAR
#undef GATE8
#undef GATE6
#undef GATE4
#undef GATE0
}

// ---------------- fallback (ws too small): naive fp32 ----------------------
__global__ __launch_bounds__(256) void toeplitz_naive(
    const float* __restrict__ x, const float* __restrict__ fr,
    const float* __restrict__ fc, const float* __restrict__ bias,
    float* __restrict__ out) {
  __shared__ float sx[1024], sfr[1024], sfc[1024];
  const int m = blockIdx.x;
  for (int i = threadIdx.x; i < 1024; i += 256) {
    sx[i]  = x[(size_t)m * 1024 + i];
    sfr[i] = fr[i];
    sfc[i] = fc[i];
  }
  __syncthreads();
  for (int q = 0; q < 4; ++q) {
    const int o = threadIdx.x + q * 256;
    float acc = bias[o];
    for (int i = 0; i <= o; ++i)       acc += sx[i] * sfc[o - i];
    for (int i = o + 1; i < 1024; ++i) acc += sx[i] * sfr[i - o];
    out[(size_t)m * 1024 + o] = acc;
  }
}

extern "C" void kernel_launch(void* const* d_in, const int* in_sizes, int n_in,
                              void* d_out, int out_size, void* d_ws, size_t ws_size,
                              hipStream_t stream) {
  const float* x    = (const float*)d_in[0];
  const float* fr   = (const float*)d_in[1];
  const float* fc   = (const float*)d_in[2];
  const float* bias = (const float*)d_in[3];
  float* out = (float*)d_out;

  const size_t T_BYTES  = (size_t)2 * 1024 * 1024;
  const size_t XB_BYTES = (size_t)32768 * 1024 * 2;

  if (ws_size >= T_BYTES + XB_BYTES) {
    ushort* T  = (ushort*)d_ws;
    ushort* XB = (ushort*)((char*)d_ws + T_BYTES);
    build_T_kernel<<<dim3(512), dim3(256), 0, stream>>>(fr, fc, T);
    convert_x_kernel<<<dim3(2048), dim3(256), 0, stream>>>(x, XB);
    gemm_bf16_p8<<<dim3(512), dim3(512), 0, stream>>>(XB, T, bias, out);
  } else {
    toeplitz_naive<<<dim3(32768), dim3(256), 0, stream>>>(x, fr, fc, bias, out);
  }
}